// Round 5
// baseline (93.263 us; speedup 1.0000x reference)
//
#include <hip/hip_runtime.h>
#include <cfloat>
#include <stdint.h>

#define B_ 16
#define N_ 4096
#define M_ 1024
#define EPS_ 1e-12f

__device__ __forceinline__ uint32_t umin3(uint32_t a, uint32_t b, uint32_t c) {
    return min(a, min(b, c));                    // -> v_min3_u32
}
__device__ __forceinline__ uint32_t umed3(uint32_t a, uint32_t b, uint32_t c) {
    return max(min(a, b), min(max(a, b), c));    // -> v_med3_u32
}

// Fused kernel, 2048 blocks, role = blockIdx&1.
// role 0 (cd1): s=tid&15 owns m-split, g=tid>>4 owns 4 points; per 2 pairs:
//   6 fma + 1 min3 (v_min3_f32) on t = |s|^2 - 2 p.s (|p|^2 added post-min).
// role 1 (knn -> cd2 + normal loss): s=tid&63 scans n (full wave), wave w
//   owns 4 m-chains; per 2 pairs/chain: 2 add + 6 fma + 2 and_or + min3 +
//   med3 + min on packed keys (bits(d^2)&~0xFFF)|n (d^2>=0 so uint order ==
//   float order; low 12 bits break ties toward smaller n like top_k).
//   One ds_read_b128 feeds 4 chains. Exact distances recomputed for winners.
__global__ __launch_bounds__(256, 8) void fused_kernel(const float* __restrict__ shape_xyz,
                                                       const float* __restrict__ skel_xyz,
                                                       const float* __restrict__ skel_nori,
                                                       float* __restrict__ out)
{
    __shared__ float4 ls4[1024];   // 16 KB
    __shared__ float ws[4];

    const int role = blockIdx.x & 1;
    const int id   = blockIdx.x >> 1;      // 0..1023
    const int b    = id >> 6;
    const int sub  = id & 63;

    float v = 0.0f;

    if (role == 0) {
        // ----------------- cd1 -----------------
        const float* skb = skel_xyz + (size_t)b * M_ * 3;
        for (int i = threadIdx.x; i < M_; i += 256) {
            const float x = skb[i * 3 + 0];
            const float y = skb[i * 3 + 1];
            const float z = skb[i * 3 + 2];
            ls4[i] = make_float4(x, y, z, fmaf(x, x, fmaf(y, y, z * z)));
        }
        __syncthreads();

        const int s  = threadIdx.x & 15;
        const int g  = threadIdx.x >> 4;
        const int n0 = sub * 64 + g * 4;

        const float* p = shape_xyz + ((size_t)b * N_ + n0) * 6;
        float m2x[4], m2y[4], m2z[4], pp[4], best[4];
#pragma unroll
        for (int k = 0; k < 4; ++k) {
            const float x = p[k * 6 + 0];
            const float y = p[k * 6 + 1];
            const float z = p[k * 6 + 2];
            m2x[k] = -2.0f * x; m2y[k] = -2.0f * y; m2z[k] = -2.0f * z;
            pp[k]  = fmaf(x, x, fmaf(y, y, z * z));
            best[k] = FLT_MAX;
        }

#pragma unroll 4
        for (int t = 0; t < 32; ++t) {         // 2 m per iter: t*32+s, t*32+16+s
            const float4 sv0 = ls4[t * 32 + s];
            const float4 sv1 = ls4[t * 32 + 16 + s];
#pragma unroll
            for (int k = 0; k < 4; ++k) {
                const float t0 = fmaf(m2x[k], sv0.x, fmaf(m2y[k], sv0.y, fmaf(m2z[k], sv0.z, sv0.w)));
                const float t1 = fmaf(m2x[k], sv1.x, fmaf(m2y[k], sv1.y, fmaf(m2z[k], sv1.z, sv1.w)));
                best[k] = fminf(best[k], fminf(t0, t1));   // -> v_min3_f32
            }
        }

#pragma unroll
        for (int off = 1; off < 16; off <<= 1) {
#pragma unroll
            for (int k = 0; k < 4; ++k) best[k] = fminf(best[k], __shfl_xor(best[k], off));
        }
        if (s == 0) {
#pragma unroll
            for (int k = 0; k < 4; ++k) v += sqrtf(fmaxf(best[k] + pp[k], EPS_));
            v *= 1e-4f;
        }
    } else {
        // ----------------- knn (cd2 + normal loss) -----------------
        const int s  = threadIdx.x & 63;           // full-wave n-split
        const int w  = threadIdx.x >> 6;           // wave id 0..3
        const int m0 = sub * 16 + w * 4;           // 4 chains per lane

        float m2x[4], m2y[4], m2z[4], aa[4];
        uint32_t k1[4], k2[4];
        {
            const float* sq = skel_xyz + ((size_t)b * M_ + m0) * 3;
#pragma unroll
            for (int c = 0; c < 4; ++c) {
                const float x = sq[c * 3 + 0];
                const float y = sq[c * 3 + 1];
                const float z = sq[c * 3 + 2];
                m2x[c] = -2.0f * x; m2y[c] = -2.0f * y; m2z[c] = -2.0f * z;
                aa[c]  = fmaf(x, x, fmaf(y, y, z * z));
                k1[c] = 0xFFFFFFFFu; k2[c] = 0xFFFFFFFFu;
            }
        }

        const uint32_t HI = 0xFFFFF000u;
        const float* sb = shape_xyz + (size_t)b * N_ * 6;

        for (int ph = 0; ph < 4; ++ph) {
            __syncthreads();                       // previous phase fully read
            for (int i = threadIdx.x; i < 1024; i += 256) {
                const float* pt = sb + (size_t)(ph * 1024 + i) * 6;
                const float x = pt[0], y = pt[1], z = pt[2];
                ls4[i] = make_float4(x, y, z, fmaf(x, x, fmaf(y, y, z * z)));
            }
            __syncthreads();
            const uint32_t nb = (uint32_t)(ph * 1024);

#pragma unroll 2
            for (int j = 0; j < 8; ++j) {          // 2 points per iter
                const int nl = j * 128 + s;
                const float4 qA = ls4[nl];
                const float4 qB = ls4[nl + 64];
                const uint32_t gnA = nb + (uint32_t)nl;
                const uint32_t gnB = gnA + 64u;
#pragma unroll
                for (int c = 0; c < 4; ++c) {
                    const float tA = fmaf(m2x[c], qA.x, fmaf(m2y[c], qA.y, fmaf(m2z[c], qA.z, qA.w + aa[c])));
                    const float tB = fmaf(m2x[c], qB.x, fmaf(m2y[c], qB.y, fmaf(m2z[c], qB.z, qB.w + aa[c])));
                    const uint32_t kA = (__float_as_uint(tA) & HI) | gnA;
                    const uint32_t kB = (__float_as_uint(tB) & HI) | gnB;
                    k2[c] = min(k2[c], umed3(k1[c], kA, kB));
                    k1[c] = umin3(k1[c], kA, kB);
                }
            }
        }

        // butterfly top-2 merge across all 64 lanes
#pragma unroll
        for (int off = 1; off < 64; off <<= 1) {
#pragma unroll
            for (int c = 0; c < 4; ++c) {
                const uint32_t o1 = (uint32_t)__shfl_xor((int)k1[c], off);
                const uint32_t o2 = (uint32_t)__shfl_xor((int)k2[c], off);
                const uint32_t nk2 = min(min(k2[c], o2), max(k1[c], o1));
                k1[c] = min(k1[c], o1);
                k2[c] = nk2;
            }
        }

        if (s == 0) {
            const float* no = skel_nori + ((size_t)b * M_ + m0) * 3;
            const float kN = 0.001f * 0.5f / (float)B_;
#pragma unroll
            for (int c = 0; c < 4; ++c) {
                const int i1 = (int)(k1[c] & 0xFFFu);
                const int i2 = (int)(k2[c] & 0xFFFu);
                const float* p1 = sb + (size_t)i1 * 6;
                const float* p2 = sb + (size_t)i2 * 6;
                // exact nearest distance (removes key quantization from cd2)
                const float ax = -0.5f * m2x[c], ay = -0.5f * m2y[c], az = -0.5f * m2z[c];
                const float dx = ax - p1[0], dy = ay - p1[1], dz = az - p1[2];
                const float d2 = fmaf(dx, dx, fmaf(dy, dy, dz * dz));
                const float q0 = no[c * 3 + 0], q1 = no[c * 3 + 1], q2 = no[c * 3 + 2];
                const float dot1 = q0 * p1[3] + q1 * p1[4] + q2 * p1[5];
                const float dot2 = q0 * p2[3] + q1 * p2[4] + q2 * p2[5];
                v += sqrtf(fmaxf(d2, EPS_)) * 1e-4f + (fabsf(dot1) + fabsf(dot2)) * kN;
            }
        }
    }

    // block reduction + one atomic per block
#pragma unroll
    for (int off = 32; off > 0; off >>= 1) v += __shfl_down(v, off);
    if ((threadIdx.x & 63) == 0) ws[threadIdx.x >> 6] = v;
    __syncthreads();
    if (threadIdx.x == 0) atomicAdd(out, ws[0] + ws[1] + ws[2] + ws[3]);
}

extern "C" void kernel_launch(void* const* d_in, const int* in_sizes, int n_in,
                              void* d_out, int out_size, void* d_ws, size_t ws_size,
                              hipStream_t stream) {
    const float* shape_xyz = (const float*)d_in[0];  // (16, 4096, 6)
    const float* skel_xyz  = (const float*)d_in[1];  // (16, 1024, 3)
    const float* skel_nori = (const float*)d_in[2];  // (16, 1024, 3)
    float* out = (float*)d_out;                      // scalar

    hipMemsetAsync(out, 0, sizeof(float), stream);   // d_out poisoned each call
    fused_kernel<<<2048, 256, 0, stream>>>(shape_xyz, skel_xyz, skel_nori, out);
}